// Round 2
// baseline (42018.491 us; speedup 1.0000x reference)
//
#include <hip/hip_runtime.h>
#include <stdint.h>

typedef unsigned short u16;
typedef u16    u16x8  __attribute__((ext_vector_type(8)));
typedef __bf16 bf16x8 __attribute__((ext_vector_type(8)));
typedef float  f32x4  __attribute__((ext_vector_type(4)));

constexpr int FEAT   = 161;
constexpr int HID    = 176;
constexpr int SEQL   = 456;
constexpr int NBATCH = 512;

// Fragment-stream offsets, units of one fragment = 64 lanes * 8 bf16 = 512 u16 = 1KB.
// B-frag for mfma_f32_16x16x32_bf16: lane l, elem j holds W[nt*16 + (l&15)][ks*32 + (l>>4)*8 + j]
constexpr int FR_GH  = 0;     // Wdh         C=176 K=161  NT=11 KS=6
constexpr int FR_XH  = 66;    // Whr         C=161 K=176  NT=11 KS=6
constexpr int FR_ZH  = 132;   // Wfr(offdiag) C=161 K=161 NT=11 KS=6
constexpr int FR_AL  = 198;   // Wwc         C=161 K=322  NT=11 KS=11
constexpr int FR_L1  = 319;   // [Wih|Whh]   C=704 K=498  NT=44 KS=16
constexpr int FR_L2  = 1023;  // [Wih2|Whh2] C=704 K=352  NT=44 KS=11
constexpr int FR_END = 1507;

// float scratch offsets (in g_wsF floats)
constexpr int WF_B1 = 0, WF_B2 = 704, WF_WDIAG = 1408, WF_INVM = 1600, WF_ACC = 2060;

// Module-scope device scratch: avoids any assumption about ws_size.
// Fully rewritten on every kernel_launch call (graph-safe, no cross-call state).
__device__ u16   g_wfr[(size_t)FR_END * 512];
__device__ float g_wsF[2064];

__device__ __forceinline__ u16 f2bf(float x) {
  union { float f; uint32_t u; } v; v.f = x;
  uint32_t r = (v.u + 0x7fffu + ((v.u >> 16) & 1u)) >> 16;   // RNE
  return (u16)r;
}
__device__ __forceinline__ float bf2f(u16 b) {
  union { uint32_t u; float f; } v; v.u = ((uint32_t)b) << 16;
  return v.f;
}
__device__ __forceinline__ float sigm(float x) { return 1.f / (1.f + __expf(-x)); }
__device__ __forceinline__ float tanh_f(float x) {
  float e = __expf(-2.f * fabsf(x));       // in (0,1], no overflow
  float t = (1.f - e) / (1.f + e);
  return x < 0.f ? -t : t;
}
__device__ __forceinline__ bf16x8 ldfrag(int fidx, int l) {
  const u16x8* p = reinterpret_cast<const u16x8*>(g_wfr + ((size_t)fidx * 64 + l) * 8);
  return __builtin_bit_cast(bf16x8, *p);
}

// Pack W = [W1 | W2] (row-major [C][K1], [C][K2]) into the MFMA B-fragment stream.
__global__ void pack_frags(const float* __restrict__ W1, int K1,
                           const float* __restrict__ W2, int K2,
                           int C, int KS, int frbase, int zdiag)
{
  const int l   = threadIdx.x;          // 64 threads
  const int fid = blockIdx.x;           // nt*KS + ks
  const int nt  = fid / KS, ks = fid % KS;
  const int c   = nt * 16 + (l & 15);
  const int K   = K1 + K2;
  u16x8 o;
  #pragma unroll
  for (int j = 0; j < 8; ++j) {
    int k = ks * 32 + (l >> 4) * 8 + j;
    float v = 0.f;
    if (c < C && k < K) {
      v = (k < K1) ? W1[(size_t)c * K1 + k] : W2[(size_t)c * K2 + (k - K1)];
      if (zdiag && c == k) v = 0.f;     // FeatureRegression off-diagonal mask
    }
    o[j] = f2bf(v);
  }
  *reinterpret_cast<u16x8*>(g_wfr + (((size_t)frbase + fid) * 64 + l) * 8) = o;
}

__global__ void prep_misc(const float* __restrict__ bih,  const float* __restrict__ bhh,
                          const float* __restrict__ bih2, const float* __restrict__ bhh2,
                          const float* __restrict__ Wdx)
{
  int tid = threadIdx.x;                // 704 threads, 1 block
  if (tid < 704) { g_wsF[WF_B1 + tid] = bih[tid] + bhh[tid]; g_wsF[WF_B2 + tid] = bih2[tid] + bhh2[tid]; }
  if (tid < FEAT) g_wsF[WF_WDIAG + tid] = Wdx[(size_t)tid * FEAT + tid];
  if (tid == 0)  g_wsF[WF_ACC] = 0.f;
}

__global__ __launch_bounds__(256) void msum_kernel(const float* __restrict__ masks)
{
  const int t = blockIdx.x;
  float s = 0.f;
  for (int idx = threadIdx.x; idx < NBATCH * FEAT; idx += 256) {
    int b = idx / FEAT, f = idx - FEAT * b;
    s += masks[((size_t)b * SEQL + t) * FEAT + f];
  }
  #pragma unroll
  for (int off = 32; off; off >>= 1) s += __shfl_down(s, off, 64);
  __shared__ float red[4];
  if ((threadIdx.x & 63) == 0) red[threadIdx.x >> 6] = s;
  __syncthreads();
  if (threadIdx.x == 0) g_wsF[WF_INVM + t] = 1.f / (red[0] + red[1] + red[2] + red[3] + 1e-5f);
}

// Main: 32 blocks x 512 threads (8 waves). Block owns 16 batch rows for all 456 steps.
__global__ __launch_bounds__(512) void rits_main(
    const float* __restrict__ values, const float* __restrict__ masks,
    const float* __restrict__ deltas,
    const float* __restrict__ bdh, const float* __restrict__ bdx,
    const float* __restrict__ bhr, const float* __restrict__ bfr,
    const float* __restrict__ bwc,
    const float* __restrict__ Wo,  const float* __restrict__ bo,
    float* __restrict__ out)
{
  // LDS arena (u16 units). Pads beyond valid K are zero-initialized once and never rewritten.
  constexpr int AB1 = 0,     S_AB1 = 520;  // LSTM1 A: [c_c(0:161)|m(161:322)|h0(322:498)]
  constexpr int AB2 = 8320,  S_AB2 = 376;  // LSTM2 A: [h0(0:176)|h_dec(176:352)]; x_h A = cols 176+
  constexpr int AD  = 14336, S_AD  = 200;  // d (gamma_h A); aliased as x_c (z_h A) after p1
  constexpr int AAL = 17536, S_AAL = 360;  // alpha A: [gamma_x(0:161)|m(161:322)]
  constexpr int XS  = 23296, S_XS  = 168;  // fp32 x values [16][168]
  constexpr int RED = 28672;               // 8 fp32 wave partials
  constexpr int ARENA = 28688;             // 57376 B
  __shared__ alignas(16) u16 sA[ARENA];

  const int tid = threadIdx.x;
  const int w = tid >> 6, l = tid & 63;
  const int lr = l & 15, kg = l >> 4;      // A-row = lr ; k-group = kg ; D: row=kg*4+ii col=lr
  const int r0 = blockIdx.x * 16;

  float* XSf = reinterpret_cast<float*>(sA + XS);
  const float* b1    = g_wsF + WF_B1;
  const float* b2    = g_wsF + WF_B2;
  const float* wdiag = g_wsF + WF_WDIAG;
  const float* invm  = g_wsF + WF_INVM;
  float* imp = out + 513;

  // Per-lane persistent state (C-layout ownership: row = kg*4+ii, col = j*16+lr, j = w+8*jj)
  float h_reg[2][4]  = {}, c_reg[2][4] = {}, c0_reg[2][4] = {};
  float al_reg[2][4] = {}, xh_reg[2][4] = {}, h0_reg[2][4] = {};
  float lossAcc = 0.f;

  for (int i = tid; i < ARENA; i += 512) sA[i] = 0;
  __syncthreads();

#define LDA(BASE, STRIDE, BASECOL, KS_) \
  __builtin_bit_cast(bf16x8, *reinterpret_cast<const u16x8*>( \
      sA + (BASE) + lr * (STRIDE) + (BASECOL) + (KS_) * 32 + kg * 8))
#define MFMA(A_, B_, C_) __builtin_amdgcn_mfma_f32_16x16x32_bf16((A_), (B_), (C_), 0, 0, 0)

  for (int t = 0; t < SEQL; ++t) {
    // ---- p0: load x,m,d ; gamma_x = exp(-relu(d*wdiag+bdx)) ----
    for (int e = tid; e < 16 * FEAT; e += 512) {
      int r = e / FEAT, f = e - FEAT * r;
      size_t g = ((size_t)(r0 + r) * SEQL + t) * FEAT + f;
      float xv = values[g], mv = masks[g], dv = deltas[g];
      XSf[r * S_XS + f] = xv;
      sA[AD + r * S_AD + f] = f2bf(dv);
      float gx = __expf(-fmaxf(dv * wdiag[f] + bdx[f], 0.f));
      u16 mb = f2bf(mv);                       // 0/1 exact in bf16
      sA[AAL + r * S_AAL + f]        = f2bf(gx);
      sA[AAL + r * S_AAL + FEAT + f] = mb;
      sA[AB1 + r * S_AB1 + FEAT + f] = mb;
    }
    __syncthreads();
    const float invms = invm[t];

    // ---- p1: gamma_h = exp(-relu(d@Wdh^T+bdh)); h_dec = h*gamma_h ; alpha = [gx|m]@Wwc^T+bwc ----
    #pragma unroll
    for (int jj = 0; jj < 2; ++jj) {
      const int j = w + 8 * jj;
      if (j < 11) {
        f32x4 ag = {0.f,0.f,0.f,0.f};
        #pragma unroll
        for (int ks = 0; ks < 6; ++ks)
          ag = MFMA(LDA(AD, S_AD, 0, ks), ldfrag(FR_GH + j * 6 + ks, l), ag);
        f32x4 aa = {0.f,0.f,0.f,0.f};
        #pragma unroll
        for (int ks = 0; ks < 11; ++ks)
          aa = MFMA(LDA(AAL, S_AAL, 0, ks), ldfrag(FR_AL + j * 11 + ks, l), aa);
        const int col = j * 16 + lr;           // < 176 always
        float bdhv = bdh[col];
        #pragma unroll
        for (int ii = 0; ii < 4; ++ii) {
          int r = kg * 4 + ii;
          float gh = __expf(-fmaxf(ag[ii] + bdhv, 0.f));
          float hd = h_reg[jj][ii] * gh;
          sA[AB2 + r * S_AB2 + HID + col] = f2bf(hd);
        }
        if (col < FEAT) {
          float bwcv = bwc[col];
          #pragma unroll
          for (int ii = 0; ii < 4; ++ii) al_reg[jj][ii] = aa[ii] + bwcv;
        }
      }
    }
    __syncthreads();

    // ---- p2: x_h = h_dec@Whr^T+bhr ; x_c = m*x+(1-m)*x_h -> AD(as x_c) ----
    #pragma unroll
    for (int jj = 0; jj < 2; ++jj) {
      const int j = w + 8 * jj;
      if (j < 11) {
        f32x4 ax = {0.f,0.f,0.f,0.f};
        #pragma unroll
        for (int ks = 0; ks < 6; ++ks)
          ax = MFMA(LDA(AB2, S_AB2, HID, ks), ldfrag(FR_XH + j * 6 + ks, l), ax);
        const int col = j * 16 + lr;
        if (col < FEAT) {
          float bv = bhr[col];
          #pragma unroll
          for (int ii = 0; ii < 4; ++ii) {
            int r = kg * 4 + ii;
            float xh = ax[ii] + bv;
            xh_reg[jj][ii] = xh;
            float xv = XSf[r * S_XS + col];
            float mv = bf2f(sA[AAL + r * S_AAL + FEAT + col]);
            float xc = mv * xv + (1.f - mv) * xh;
            sA[AD + r * S_AD + col] = f2bf(xc);
          }
        }
      }
    }
    __syncthreads();

    // ---- p3: z_h = x_c@Wfr_m^T+bfr ; c_h, c_c, loss, imputation write ----
    #pragma unroll
    for (int jj = 0; jj < 2; ++jj) {
      const int j = w + 8 * jj;
      if (j < 11) {
        f32x4 az = {0.f,0.f,0.f,0.f};
        #pragma unroll
        for (int ks = 0; ks < 6; ++ks)
          az = MFMA(LDA(AD, S_AD, 0, ks), ldfrag(FR_ZH + j * 6 + ks, l), az);
        const int col = j * 16 + lr;
        if (col < FEAT) {
          float bv = bfr[col];
          #pragma unroll
          for (int ii = 0; ii < 4; ++ii) {
            int r = kg * 4 + ii;
            float zh = az[ii] + bv;
            float al = al_reg[jj][ii];
            float xh = xh_reg[jj][ii];
            float ch = al * zh + (1.f - al) * xh;
            float xv = XSf[r * S_XS + col];
            float mv = bf2f(sA[AAL + r * S_AAL + FEAT + col]);
            float cc = mv * xv + (1.f - mv) * ch;
            imp[((size_t)(r0 + r) * SEQL + t) * FEAT + col] = cc;
            sA[AB1 + r * S_AB1 + col] = f2bf(cc);
            lossAcc += (fabsf(xv - xh) + fabsf(xv - zh) + fabsf(xv - ch)) * mv * invms;
          }
        }
      }
    }
    __syncthreads();

    // ---- p5: LSTM1 gates = [c_c|m|h0]@[Wih|Whh]^T + (bih+bhh) ----
    // NOTE: new h0 goes to registers + AB2 (which no p5 wave reads). Writing it to
    // AB1 here would race with other waves' A-reads of the h0_prev columns.
    #pragma unroll
    for (int jj = 0; jj < 2; ++jj) {
      const int j = w + 8 * jj;
      if (j < 11) {
        f32x4 ai={0,0,0,0}, af2={0,0,0,0}, ag2={0,0,0,0}, ao={0,0,0,0};
        #pragma unroll
        for (int ks = 0; ks < 16; ++ks) {
          bf16x8 a = LDA(AB1, S_AB1, 0, ks);
          ai  = MFMA(a, ldfrag(FR_L1 + (j)      * 16 + ks, l), ai);
          af2 = MFMA(a, ldfrag(FR_L1 + (11 + j) * 16 + ks, l), af2);
          ag2 = MFMA(a, ldfrag(FR_L1 + (22 + j) * 16 + ks, l), ag2);
          ao  = MFMA(a, ldfrag(FR_L1 + (33 + j) * 16 + ks, l), ao);
        }
        const int col = j * 16 + lr;
        float bi = b1[col], bf = b1[HID + col], bg = b1[2 * HID + col], bo_ = b1[3 * HID + col];
        #pragma unroll
        for (int ii = 0; ii < 4; ++ii) {
          int r = kg * 4 + ii;
          float iG = sigm(ai[ii] + bi);
          float fG = sigm(af2[ii] + bf);
          float gG = tanh_f(ag2[ii] + bg);
          float oG = sigm(ao[ii] + bo_);
          float cn = fG * c0_reg[jj][ii] + iG * gG;
          c0_reg[jj][ii] = cn;
          float h0v = oG * tanh_f(cn);
          h0_reg[jj][ii] = h0v;
          sA[AB2 + r * S_AB2 + col] = f2bf(h0v);      // LSTM2 input x = h0
        }
      }
    }
    __syncthreads();

    // ---- p6: LSTM2 gates = [h0|h_dec]@[Wih2|Whh2]^T + (bih2+bhh2) ; h,c in regs ----
    // Also commit h0 -> AB1[2*FEAT+..] for next step's p5 (p6 reads only AB2: no race).
    #pragma unroll
    for (int jj = 0; jj < 2; ++jj) {
      const int j = w + 8 * jj;
      if (j < 11) {
        const int col = j * 16 + lr;
        #pragma unroll
        for (int ii = 0; ii < 4; ++ii)
          sA[AB1 + (kg * 4 + ii) * S_AB1 + 2 * FEAT + col] = f2bf(h0_reg[jj][ii]);
        f32x4 ai={0,0,0,0}, af2={0,0,0,0}, ag2={0,0,0,0}, ao={0,0,0,0};
        #pragma unroll
        for (int ks = 0; ks < 11; ++ks) {
          bf16x8 a = LDA(AB2, S_AB2, 0, ks);
          ai  = MFMA(a, ldfrag(FR_L2 + (j)      * 11 + ks, l), ai);
          af2 = MFMA(a, ldfrag(FR_L2 + (11 + j) * 11 + ks, l), af2);
          ag2 = MFMA(a, ldfrag(FR_L2 + (22 + j) * 11 + ks, l), ag2);
          ao  = MFMA(a, ldfrag(FR_L2 + (33 + j) * 11 + ks, l), ao);
        }
        float bi = b2[col], bf = b2[HID + col], bg = b2[2 * HID + col], bo_ = b2[3 * HID + col];
        #pragma unroll
        for (int ii = 0; ii < 4; ++ii) {
          float iG = sigm(ai[ii] + bi);
          float fG = sigm(af2[ii] + bf);
          float gG = tanh_f(ag2[ii] + bg);
          float oG = sigm(ao[ii] + bo_);
          float cn = fG * c_reg[jj][ii] + iG * gG;
          c_reg[jj][ii] = cn;
          h_reg[jj][ii] = oG * tanh_f(cn);
        }
      }
    }
    __syncthreads();
  }

  // ---- predictions = sigmoid(h_final @ Wo^T + bo) ----
  float* hf = reinterpret_cast<float*>(sA + AB1);   // reuse arena as fp32 [16][176]
  #pragma unroll
  for (int jj = 0; jj < 2; ++jj) {
    const int j = w + 8 * jj;
    if (j < 11) {
      const int col = j * 16 + lr;
      #pragma unroll
      for (int ii = 0; ii < 4; ++ii) hf[(kg * 4 + ii) * HID + col] = h_reg[jj][ii];
    }
  }
  __syncthreads();
  if (tid < 16) {
    float s = bo[0];
    for (int k = 0; k < HID; ++k) s += hf[tid * HID + k] * Wo[k];
    out[1 + r0 + tid] = sigm(s);
  }

  // ---- loss partial reduction -> atomicAdd ----
  float v = lossAcc;
  #pragma unroll
  for (int off = 32; off; off >>= 1) v += __shfl_down(v, off, 64);
  float* red = reinterpret_cast<float*>(sA + RED);
  if (l == 0) red[w] = v;
  __syncthreads();
  if (tid == 0) {
    float s = 0.f;
    #pragma unroll
    for (int i = 0; i < 8; ++i) s += red[i];
    atomicAdd(&g_wsF[WF_ACC], s);
  }
#undef LDA
#undef MFMA
}

__global__ void finalize_kernel(float* __restrict__ out) {
  if (threadIdx.x == 0 && blockIdx.x == 0) out[0] = g_wsF[WF_ACC] * (1.f / (float)SEQL);
}

extern "C" void kernel_launch(void* const* d_in, const int* in_sizes, int n_in,
                              void* d_out, int out_size, void* d_ws, size_t ws_size,
                              hipStream_t stream)
{
  const float* values = (const float*)d_in[0];
  const float* masks  = (const float*)d_in[1];
  const float* deltas = (const float*)d_in[2];
  // d_in[3]=labels, d_in[4]=is_train : unused by outputs
  const float* Wdh  = (const float*)d_in[5];
  const float* bdh  = (const float*)d_in[6];
  const float* Wdx  = (const float*)d_in[7];
  const float* bdx  = (const float*)d_in[8];
  const float* Whr  = (const float*)d_in[9];
  const float* bhr  = (const float*)d_in[10];
  const float* Wfr  = (const float*)d_in[11];
  const float* bfr  = (const float*)d_in[12];
  const float* Wwc  = (const float*)d_in[13];
  const float* bwc  = (const float*)d_in[14];
  const float* Wih  = (const float*)d_in[15];
  const float* Whh  = (const float*)d_in[16];
  const float* bih  = (const float*)d_in[17];
  const float* bhh  = (const float*)d_in[18];
  const float* Wih2 = (const float*)d_in[19];
  const float* Whh2 = (const float*)d_in[20];
  const float* bih2 = (const float*)d_in[21];
  const float* bhh2 = (const float*)d_in[22];
  const float* Wo   = (const float*)d_in[23];
  const float* bo   = (const float*)d_in[24];

  // Repack weights -> bf16 MFMA B-fragment streams (runs every call)
  pack_frags<<<11 * 6,  64, 0, stream>>>(Wdh,  161, Wdh,  0,   176, 6,  FR_GH, 0);
  pack_frags<<<11 * 6,  64, 0, stream>>>(Whr,  176, Whr,  0,   161, 6,  FR_XH, 0);
  pack_frags<<<11 * 6,  64, 0, stream>>>(Wfr,  161, Wfr,  0,   161, 6,  FR_ZH, 1);
  pack_frags<<<11 * 11, 64, 0, stream>>>(Wwc,  322, Wwc,  0,   161, 11, FR_AL, 0);
  pack_frags<<<44 * 16, 64, 0, stream>>>(Wih,  322, Whh,  176, 704, 16, FR_L1, 0);
  pack_frags<<<44 * 11, 64, 0, stream>>>(Wih2, 176, Whh2, 176, 704, 11, FR_L2, 0);
  prep_misc<<<1, 704, 0, stream>>>(bih, bhh, bih2, bhh2, Wdx);
  msum_kernel<<<SEQL, 256, 0, stream>>>(masks);

  rits_main<<<NBATCH / 16, 512, 0, stream>>>(values, masks, deltas,
                                             bdh, bdx, bhr, bfr, bwc, Wo, bo,
                                             (float*)d_out);
  finalize_kernel<<<1, 64, 0, stream>>>((float*)d_out);
}